// Round 11
// baseline (242.128 us; speedup 1.0000x reference)
//
#include <hip/hip_runtime.h>
#include <cstddef>
#include <cstdint>

#define T_SEQ 100

typedef __attribute__((ext_vector_type(8))) short bfrag;
typedef __attribute__((ext_vector_type(4))) float f4;

union FragU { uint32_t u[4]; bfrag v; };

__device__ __forceinline__ float fast_tanh(float x) {
    float e = __expf(2.0f * x);
    float r = __builtin_amdgcn_rcpf(e + 1.0f);
    return 1.0f - 2.0f * r;
}

__device__ __forceinline__ float exp2_fast(float x) {
#if __has_builtin(__builtin_amdgcn_exp2f)
    return __builtin_amdgcn_exp2f(x);
#else
    return __expf(x * 0.6931471805599453f);
#endif
}

// tanh(o)*scale = scale - 2*scale / (2^(o*2*log2e) + 1)
__device__ __forceinline__ float tanh_mul(float o, float scale, float s2) {
    float rr = __builtin_amdgcn_rcpf(exp2_fast(o * 2.8853900817779268f) + 1.0f);
    return fmaf(-s2, rr, scale);
}

#if __has_builtin(__builtin_amdgcn_cvt_pk_bf16_f32)
typedef __attribute__((ext_vector_type(2))) __bf16 bf16x2;
__device__ __forceinline__ void pack8(const float a[8], bfrag& out) {
    FragU O;
    #pragma unroll
    for (int q = 0; q < 4; ++q) {
        bf16x2 p = __builtin_amdgcn_cvt_pk_bf16_f32(a[2 * q], a[2 * q + 1]);
        O.u[q] = __builtin_bit_cast(uint32_t, p);
    }
    out = O.v;
}
#else
__device__ __forceinline__ uint32_t bf16rne(float f) {
    uint32_t u = __float_as_uint(f);
    return (u + 0x7FFFu + ((u >> 16) & 1u)) >> 16;
}
__device__ __forceinline__ void pack8(const float a[8], bfrag& out) {
    FragU O;
    #pragma unroll
    for (int q = 0; q < 4; ++q)
        O.u[q] = bf16rne(a[2 * q]) | (bf16rne(a[2 * q + 1]) << 16);
    out = O.v;
}
#endif

__device__ __forceinline__ f4 mfma_(bfrag a, bfrag b, f4 c) {
    return __builtin_amdgcn_mfma_f32_16x16x32_bf16(a, b, c, 0, 0, 0);
}

// ============================================================================
// Serial recurrence: one wave = 16 elements. PAIRED stale-base Euler:
// per pair (t,t+1) both fevals start from z_t (independent -> interleave;
// chain depth = 50 links, not 100). z_{t+1} uses exact Euler; z_{t+2} adds
// f(z_t; x_{t+1}) (stale base; error ~4e-6/pair, ~2e-4 total on z).
// z rows stored as ONE dwordx4/lane in a permuted layout (mu_kernel unpacks):
// row dword d: g=d>>2, q=d&3 -> components c=(q>>1)*16+4g+2(q&1) (lo), c+1 (hi).
// 2-pair-deep x/dt prefetch (r10's latency fix, kept).
// ============================================================================
__global__ __launch_bounds__(64, 1)
void latode_serial(const float* __restrict__ dt,  const float* __restrict__ x,
                   const float* __restrict__ We1, const float* __restrict__ be1,
                   const float* __restrict__ We2, const float* __restrict__ be2,
                   const float* __restrict__ Wf1, const float* __restrict__ bf1,
                   const float* __restrict__ Wf2, const float* __restrict__ bf2,
                   uint32_t* __restrict__ zws, int B)
{
    const int l = threadIdx.x;
    const int g = l >> 4;
    const int m = l & 15;
    const int e = blockIdx.x * 16 + m;
    const int js0 = 8 * (m >> 2) + (m & 3);
    const int js1 = js0 + 4;

    float tmp[8];
    bfrag A0, A1, X0, X1, W0, W1;   // single RNE-bf16 weight fragments

    #pragma unroll
    for (int jj = 0; jj < 8; ++jj) {
        int sig = 16 * (jj >> 2) + 4 * g + (jj & 3);
        tmp[jj] = (js0 < 20) ? Wf1[sig * 20 + js0] : 0.0f;
    }
    pack8(tmp, A0);
    #pragma unroll
    for (int jj = 0; jj < 8; ++jj) {
        int sig = 16 * (jj >> 2) + 4 * g + (jj & 3);
        tmp[jj] = (js1 < 20) ? Wf1[sig * 20 + js1] : 0.0f;
    }
    pack8(tmp, A1);
    #pragma unroll
    for (int jj = 0; jj < 8; ++jj) {
        int kx = 8 * g + jj;
        tmp[jj] = (js0 < 20) ? Wf1[(32 + kx) * 20 + js0] : 0.0f;
    }
    pack8(tmp, X0);
    #pragma unroll
    for (int jj = 0; jj < 8; ++jj) {
        int kx = 8 * g + jj;
        tmp[jj] = (js1 < 20) ? Wf1[(32 + kx) * 20 + js1] : 0.0f;
    }
    pack8(tmp, X1);
    #pragma unroll
    for (int jj = 0; jj < 8; ++jj) {
        int j = 8 * g + jj;
        tmp[jj] = (j < 20) ? Wf2[j * 32 + m] : 0.0f;
    }
    pack8(tmp, W0);
    #pragma unroll
    for (int jj = 0; jj < 8; ++jj) {
        int j = 8 * g + jj;
        tmp[jj] = (j < 20) ? Wf2[j * 32 + 16 + m] : 0.0f;
    }
    pack8(tmp, W1);

    f4 bias0, bias1, cb0, cb1;
    #pragma unroll
    for (int r = 0; r < 4; ++r) {
        bias0[r] = bf2[4 * g + r];
        bias1[r] = bf2[16 + 4 * g + r];
        int j0 = 8 * g + r;     cb0[r] = (j0 < 20) ? bf1[j0] : 0.0f;
        int j1 = 8 * g + r + 4; cb1[r] = (j1 < 20) ? bf1[j1] : 0.0f;
    }

    const float* xe  = x  + (size_t)e * T_SEQ * 32;
    const float* xp  = xe + 8 * g;
    const float* dte = dt + (size_t)e * T_SEQ * 2;
    uint32_t* zrow = zws + (size_t)e * T_SEQ * 16 + 4 * g;   // lane's dwordx4 slot

    // ---- z0 encode (scalar fp32, once) ----
    float z[8];
    {
        float x0v[32];
        #pragma unroll
        for (int i = 0; i < 32; i += 4) {
            float4 v = *(const float4*)(xe + i);
            x0v[i] = v.x; x0v[i+1] = v.y; x0v[i+2] = v.z; x0v[i+3] = v.w;
        }
        float h10[10];
        #pragma unroll
        for (int r = 0; r < 10; ++r) {
            float s = be1[r];
            #pragma unroll
            for (int i = 0; i < 32; ++i) s += x0v[i] * We1[i * 10 + r];
            h10[r] = fast_tanh(s);
        }
        #pragma unroll
        for (int jj = 0; jj < 8; ++jj) {
            int sig = 16 * (jj >> 2) + 4 * g + (jj & 3);
            float s = be2[sig];
            #pragma unroll
            for (int r = 0; r < 10; ++r) s += h10[r] * We2[r * 32 + sig];
            z[jj] = fast_tanh(s);
        }
    }

    // Pair buffer: x rows for t=2p and 2p+1, dt for both (one float4).
    struct PBuf { float4 a0, b0, a1, b1; float4 d; };
    auto load_pair = [&](PBuf& Bf, int p) {
        int t0 = 2 * p; if (t0 > T_SEQ - 2) t0 = T_SEQ - 2;
        const float* xr = xp + (size_t)t0 * 32;
        Bf.a0 = *(const float4*)(xr);
        Bf.b0 = *(const float4*)(xr + 4);
        Bf.a1 = *(const float4*)(xr + 32);
        Bf.b1 = *(const float4*)(xr + 36);
        Bf.d  = *(const float4*)(dte + 2 * t0);
    };

    f4 cxA0, cxA1, cxB0, cxB1;
    float sA, sB;
    auto cx_from = [&](const PBuf& Bf) {
        float xt[8];
        bfrag xf;
        xt[0]=Bf.a0.x; xt[1]=Bf.a0.y; xt[2]=Bf.a0.z; xt[3]=Bf.a0.w;
        xt[4]=Bf.b0.x; xt[5]=Bf.b0.y; xt[6]=Bf.b0.z; xt[7]=Bf.b0.w;
        pack8(xt, xf);
        cxA0 = mfma_(X0, xf, cb0);
        cxA1 = mfma_(X1, xf, cb1);
        xt[0]=Bf.a1.x; xt[1]=Bf.a1.y; xt[2]=Bf.a1.z; xt[3]=Bf.a1.w;
        xt[4]=Bf.b1.x; xt[5]=Bf.b1.y; xt[6]=Bf.b1.z; xt[7]=Bf.b1.w;
        pack8(xt, xf);
        cxB0 = mfma_(X0, xf, cb0);
        cxB1 = mfma_(X1, xf, cb1);
        sA = (Bf.d.y - Bf.d.x) * 0.01f;
        sB = (Bf.d.w - Bf.d.z) * 0.01f;
    };

    auto store_z = [&](const float zz[8], int t) {
        bfrag zf; pack8(zz, zf);
        FragU P; P.v = zf;
        *(uint4*)(zrow + (uint32_t)t * 16) = make_uint4(P.u[0], P.u[1], P.u[2], P.u[3]);
    };

    // Super-body for pair p (t=2p, 2p+1): both fevals from base z.
    auto body_pair = [&](int t) {
        bfrag bb; pack8(z, bb);
        // Two independent P's (shared A-operand and B-fragment):
        f4 pA0 = mfma_(A0, bb, cxA0);
        f4 pA1 = mfma_(A1, bb, cxA1);
        f4 pB0 = mfma_(A0, bb, cxB0);
        f4 pB1 = mfma_(A1, bb, cxB1);
        float prA[8], prB[8];
        #pragma unroll
        for (int r = 0; r < 4; ++r) {
            prA[r]     = fmaxf(pA0[r], 0.0f);
            prA[4 + r] = fmaxf(pA1[r], 0.0f);
            prB[r]     = fmaxf(pB0[r], 0.0f);
            prB[4 + r] = fmaxf(pB1[r], 0.0f);
        }
        bfrag pfA, pfB;
        pack8(prA, pfA);
        pack8(prB, pfB);
        f4 oA0 = mfma_(W0, pfA, bias0);
        f4 oA1 = mfma_(W1, pfA, bias1);
        f4 oB0 = mfma_(W0, pfB, bias0);
        f4 oB1 = mfma_(W1, pfB, bias1);
        const float s2A = sA + sA, s2B = sB + sB;
        float kB[8];
        #pragma unroll
        for (int r = 0; r < 4; ++r) {
            z[r]      += tanh_mul(oA0[r], sA, s2A);
            z[4 + r]  += tanh_mul(oA1[r], sA, s2A);
            kB[r]      = tanh_mul(oB0[r], sB, s2B);
            kB[4 + r]  = tanh_mul(oB1[r], sB, s2B);
        }
        store_z(z, t);          // z_{t+1}
        #pragma unroll
        for (int c = 0; c < 8; ++c) z[c] += kB[c];
        store_z(z, t + 1);      // z_{t+2}
    };

    // ---- pipeline preamble ----
    PBuf Bn, Bf2;
    {
        PBuf Bc; load_pair(Bc, 0);
        cx_from(Bc);            // cx for pair 0
    }
    load_pair(Bn, 1);

    #pragma unroll 1
    for (int p = 0; p < T_SEQ / 2; p += 2) {
        load_pair(Bf2, p + 2);              // in flight across body(p)
        body_pair(2 * p);
        cx_from(Bn);                        // cx for pair p+1 (loaded 2 bodies ago)
        load_pair(Bn, p + 3);               // in flight across body(p+1)
        body_pair(2 * (p + 1));
        cx_from(Bf2);                       // cx for pair p+2
    }
}

// Parallel mu head: one thread per (e,t) row. Unpacks the permuted z layout:
// dword d: g=d>>2, q=d&3 -> component c=(q>>1)*16+4g+2(q&1) (lo), c+1 (hi).
__global__ __launch_bounds__(256, 4)
void mu_kernel(const uint32_t* __restrict__ zws,
               const float* __restrict__ Wm1, const float* __restrict__ bm1,
               const float* __restrict__ Wm2, const float* __restrict__ bm2,
               float* __restrict__ out, int nrows)
{
    int row = blockIdx.x * 256 + threadIdx.x;
    if (row >= nrows) return;
    const uint4* zp = (const uint4*)(zws + (size_t)row * 16);
    uint4 q0 = zp[0], q1 = zp[1], q2 = zp[2], q3 = zp[3];
    uint32_t du[16] = { q0.x, q0.y, q0.z, q0.w, q1.x, q1.y, q1.z, q1.w,
                        q2.x, q2.y, q2.z, q2.w, q3.x, q3.y, q3.z, q3.w };
    float zf[32];
    #pragma unroll
    for (int d = 0; d < 16; ++d) {
        int gg = d >> 2, qq = d & 3;
        int c = (qq >> 1) * 16 + 4 * gg + (qq & 1) * 2;
        uint32_t u = du[d];
        zf[c]     = __uint_as_float(u << 16);
        zf[c + 1] = __uint_as_float(u & 0xFFFF0000u);
    }
    float v[10];
    #pragma unroll
    for (int r = 0; r < 10; ++r) v[r] = bm1[r];
    #pragma unroll
    for (int i = 0; i < 32; ++i) {
        float zi = zf[i];
        #pragma unroll
        for (int r = 0; r < 10; ++r) v[r] = fmaf(zi, Wm1[i * 10 + r], v[r]);
    }
    float mu = bm2[0];
    #pragma unroll
    for (int r = 0; r < 10; ++r) mu += fast_tanh(v[r]) * Wm2[r];
    out[row] = mu;
}

// ============================================================================
// Fallback (ws too small / B not /16): fused Euler, mu in-loop (r9 structure).
// ============================================================================
__global__ __launch_bounds__(64, 1)
void latode_fused(const float* __restrict__ dt,  const float* __restrict__ x,
                  const float* __restrict__ We1, const float* __restrict__ be1,
                  const float* __restrict__ We2, const float* __restrict__ be2,
                  const float* __restrict__ Wf1, const float* __restrict__ bf1,
                  const float* __restrict__ Wf2, const float* __restrict__ bf2,
                  const float* __restrict__ Wm1, const float* __restrict__ bm1,
                  const float* __restrict__ Wm2, const float* __restrict__ bm2,
                  float* __restrict__ out, int B)
{
    const int l = threadIdx.x;
    const int g = l >> 4;
    const int m = l & 15;
    const int e = blockIdx.x * 16 + m;
    if (e >= B) return;
    const int js0 = 8 * (m >> 2) + (m & 3);
    const int js1 = js0 + 4;

    float tmp[8];
    bfrag A0, A1, X0, X1, W0, W1, M0;
    #pragma unroll
    for (int jj = 0; jj < 8; ++jj) {
        int sig = 16 * (jj >> 2) + 4 * g + (jj & 3);
        tmp[jj] = (js0 < 20) ? Wf1[sig * 20 + js0] : 0.0f;
    }
    pack8(tmp, A0);
    #pragma unroll
    for (int jj = 0; jj < 8; ++jj) {
        int sig = 16 * (jj >> 2) + 4 * g + (jj & 3);
        tmp[jj] = (js1 < 20) ? Wf1[sig * 20 + js1] : 0.0f;
    }
    pack8(tmp, A1);
    #pragma unroll
    for (int jj = 0; jj < 8; ++jj) {
        int kx = 8 * g + jj;
        tmp[jj] = (js0 < 20) ? Wf1[(32 + kx) * 20 + js0] : 0.0f;
    }
    pack8(tmp, X0);
    #pragma unroll
    for (int jj = 0; jj < 8; ++jj) {
        int kx = 8 * g + jj;
        tmp[jj] = (js1 < 20) ? Wf1[(32 + kx) * 20 + js1] : 0.0f;
    }
    pack8(tmp, X1);
    #pragma unroll
    for (int jj = 0; jj < 8; ++jj) {
        int j = 8 * g + jj;
        tmp[jj] = (j < 20) ? Wf2[j * 32 + m] : 0.0f;
    }
    pack8(tmp, W0);
    #pragma unroll
    for (int jj = 0; jj < 8; ++jj) {
        int j = 8 * g + jj;
        tmp[jj] = (j < 20) ? Wf2[j * 32 + 16 + m] : 0.0f;
    }
    pack8(tmp, W1);
    #pragma unroll
    for (int jj = 0; jj < 8; ++jj) {
        int sig = 16 * (jj >> 2) + 4 * g + (jj & 3);
        tmp[jj] = (m < 10) ? Wm1[sig * 10 + m] : 0.0f;
    }
    pack8(tmp, M0);

    f4 bias0, bias1, cb0, cb1, bmv;
    float wm2r[4];
    #pragma unroll
    for (int r = 0; r < 4; ++r) {
        bias0[r] = bf2[4 * g + r];
        bias1[r] = bf2[16 + 4 * g + r];
        int j0 = 8 * g + r;     cb0[r] = (j0 < 20) ? bf1[j0] : 0.0f;
        int j1 = 8 * g + r + 4; cb1[r] = (j1 < 20) ? bf1[j1] : 0.0f;
        int vr = 4 * g + r;
        bmv[r]  = (vr < 10) ? bm1[vr] : 0.0f;
        wm2r[r] = (vr < 10) ? Wm2[vr] : 0.0f;
    }

    const float* xe  = x  + (size_t)e * T_SEQ * 32;
    const float* dte = dt + (size_t)e * T_SEQ * 2;

    float z[8];
    {
        float x0v[32];
        #pragma unroll
        for (int i = 0; i < 32; i += 4) {
            float4 v = *(const float4*)(xe + i);
            x0v[i] = v.x; x0v[i+1] = v.y; x0v[i+2] = v.z; x0v[i+3] = v.w;
        }
        float h10[10];
        #pragma unroll
        for (int r = 0; r < 10; ++r) {
            float s = be1[r];
            #pragma unroll
            for (int i = 0; i < 32; ++i) s += x0v[i] * We1[i * 10 + r];
            h10[r] = fast_tanh(s);
        }
        #pragma unroll
        for (int jj = 0; jj < 8; ++jj) {
            int sig = 16 * (jj >> 2) + 4 * g + (jj & 3);
            float s = be2[sig];
            #pragma unroll
            for (int r = 0; r < 10; ++r) s += h10[r] * We2[r * 32 + sig];
            z[jj] = fast_tanh(s);
        }
    }

    const float bm2s = bm2[0];
    f4 cx0, cx1;
    float scale;
    {
        float4 va = *(const float4*)(xe + 8 * g);
        float4 vb = *(const float4*)(xe + 8 * g + 4);
        float2 dd = *(const float2*)(dte);
        float xt[8] = { va.x, va.y, va.z, va.w, vb.x, vb.y, vb.z, vb.w };
        bfrag xf; pack8(xt, xf);
        cx0 = mfma_(X0, xf, cb0);
        cx1 = mfma_(X1, xf, cb1);
        scale = (dd.y - dd.x) * 0.01f;
    }

    for (int t = 0; t < T_SEQ; ++t) {
        int tn = (t + 1 < T_SEQ) ? (t + 1) : t;
        const float* xr = xe + tn * 32 + 8 * g;
        float4 na = *(const float4*)(xr);
        float4 nb = *(const float4*)(xr + 4);
        float2 nd = *(const float2*)(dte + 2 * tn);
        const float s2 = scale + scale;

        bfrag bb; pack8(z, bb);
        f4 p0 = mfma_(A0, bb, cx0);
        f4 p1 = mfma_(A1, bb, cx1);
        float pr[8];
        #pragma unroll
        for (int r = 0; r < 4; ++r) {
            pr[r]     = fmaxf(p0[r], 0.0f);
            pr[4 + r] = fmaxf(p1[r], 0.0f);
        }
        bfrag pf; pack8(pr, pf);
        f4 o0 = mfma_(W0, pf, bias0);
        f4 o1 = mfma_(W1, pf, bias1);
        #pragma unroll
        for (int r = 0; r < 4; ++r) {
            z[r]     += tanh_mul(o0[r], scale, s2);
            z[4 + r] += tanh_mul(o1[r], scale, s2);
        }

        {
            float xt[8] = { na.x, na.y, na.z, na.w, nb.x, nb.y, nb.z, nb.w };
            bfrag xf; pack8(xt, xf);
            cx0 = mfma_(X0, xf, cb0);
            cx1 = mfma_(X1, xf, cb1);
            scale = (nd.y - nd.x) * 0.01f;
        }

        bfrag zf; pack8(z, zf);
        f4 vv = mfma_(M0, zf, bmv);
        float p = 0.0f;
        #pragma unroll
        for (int r = 0; r < 4; ++r) p += fast_tanh(vv[r]) * wm2r[r];
        p += __shfl_xor(p, 16, 64);
        p += __shfl_xor(p, 32, 64);
        if (l < 16) out[(size_t)e * T_SEQ + t] = p + bm2s;
    }
}

extern "C" void kernel_launch(void* const* d_in, const int* in_sizes, int n_in,
                              void* d_out, int out_size, void* d_ws, size_t ws_size,
                              hipStream_t stream) {
    const float* dt  = (const float*)d_in[0];
    const float* x   = (const float*)d_in[1];
    const float* We1 = (const float*)d_in[2];
    const float* be1 = (const float*)d_in[3];
    const float* We2 = (const float*)d_in[4];
    const float* be2 = (const float*)d_in[5];
    const float* Wf1 = (const float*)d_in[6];
    const float* bf1 = (const float*)d_in[7];
    const float* Wf2 = (const float*)d_in[8];
    const float* bf2 = (const float*)d_in[9];
    const float* Wm1 = (const float*)d_in[10];
    const float* bm1 = (const float*)d_in[11];
    const float* Wm2 = (const float*)d_in[12];
    const float* bm2 = (const float*)d_in[13];
    float* out = (float*)d_out;

    const int B = in_sizes[0] / (T_SEQ * 2);   // 8192
    const size_t zbytes = (size_t)B * T_SEQ * 32 * 2;

    if (ws_size >= zbytes && (B % 16) == 0) {
        hipLaunchKernelGGL(latode_serial, dim3(B / 16), dim3(64), 0, stream,
                           dt, x, We1, be1, We2, be2, Wf1, bf1, Wf2, bf2,
                           (uint32_t*)d_ws, B);
        int nrows = B * T_SEQ;
        hipLaunchKernelGGL(mu_kernel, dim3((nrows + 255) / 256), dim3(256), 0, stream,
                           (const uint32_t*)d_ws, Wm1, bm1, Wm2, bm2, out, nrows);
    } else {
        hipLaunchKernelGGL(latode_fused, dim3((B + 15) / 16), dim3(64), 0, stream,
                           dt, x, We1, be1, We2, be2, Wf1, bf1, Wf2, bf2,
                           Wm1, bm1, Wm2, bm2, out, B);
    }
}

// Round 12
// 241.143 us; speedup vs baseline: 1.0041x; 1.0041x over previous
//
#include <hip/hip_runtime.h>
#include <cstddef>
#include <cstdint>

#define T_SEQ 100

typedef __attribute__((ext_vector_type(8))) short bfrag;
typedef __attribute__((ext_vector_type(4))) float f4;

union FragU { uint32_t u[4]; bfrag v; };

__device__ __forceinline__ float fast_tanh(float x) {
    float e = __expf(2.0f * x);
    float r = __builtin_amdgcn_rcpf(e + 1.0f);
    return 1.0f - 2.0f * r;
}

__device__ __forceinline__ float exp2_fast(float x) {
#if __has_builtin(__builtin_amdgcn_exp2f)
    return __builtin_amdgcn_exp2f(x);
#else
    return __expf(x * 0.6931471805599453f);
#endif
}

// tanh(o)*scale = scale - 2*scale / (2^(o*2*log2e) + 1)
__device__ __forceinline__ float tanh_mul(float o, float scale, float s2) {
    float rr = __builtin_amdgcn_rcpf(exp2_fast(o * 2.8853900817779268f) + 1.0f);
    return fmaf(-s2, rr, scale);
}

#if __has_builtin(__builtin_amdgcn_cvt_pk_bf16_f32)
typedef __attribute__((ext_vector_type(2))) __bf16 bf16x2;
__device__ __forceinline__ void pack8(const float a[8], bfrag& out) {
    FragU O;
    #pragma unroll
    for (int q = 0; q < 4; ++q) {
        bf16x2 p = __builtin_amdgcn_cvt_pk_bf16_f32(a[2 * q], a[2 * q + 1]);
        O.u[q] = __builtin_bit_cast(uint32_t, p);
    }
    out = O.v;
}
#else
__device__ __forceinline__ uint32_t bf16rne(float f) {
    uint32_t u = __float_as_uint(f);
    return (u + 0x7FFFu + ((u >> 16) & 1u)) >> 16;
}
__device__ __forceinline__ void pack8(const float a[8], bfrag& out) {
    FragU O;
    #pragma unroll
    for (int q = 0; q < 4; ++q)
        O.u[q] = bf16rne(a[2 * q]) | (bf16rne(a[2 * q + 1]) << 16);
    out = O.v;
}
#endif

__device__ __forceinline__ f4 mfma_(bfrag a, bfrag b, f4 c) {
    return __builtin_amdgcn_mfma_f32_16x16x32_bf16(a, b, c, 0, 0, 0);
}

// ============================================================================
// Serial recurrence (r10 skeleton, issue-trimmed): one wave = 16 elements,
// exact Euler (1 feval/t). Packed zf carried across iterations (store fragment
// == next feval's B operand). 4-t unrolled loop, A/B buffer roles fixed (no
// rotation copies), loads placed 2-3 bodies before consumption. z rows stored
// as ONE dwordx4/lane in the r11 permuted layout (mu_kernel unpacks).
// ============================================================================
__global__ __launch_bounds__(64, 1)
void latode_serial(const float* __restrict__ dt,  const float* __restrict__ x,
                   const float* __restrict__ We1, const float* __restrict__ be1,
                   const float* __restrict__ We2, const float* __restrict__ be2,
                   const float* __restrict__ Wf1, const float* __restrict__ bf1,
                   const float* __restrict__ Wf2, const float* __restrict__ bf2,
                   uint32_t* __restrict__ zws, int B)
{
    const int l = threadIdx.x;
    const int g = l >> 4;
    const int m = l & 15;
    const int e = blockIdx.x * 16 + m;
    const int js0 = 8 * (m >> 2) + (m & 3);
    const int js1 = js0 + 4;

    float tmp[8];
    bfrag A0, A1, X0, X1, W0, W1;   // single RNE-bf16 weight fragments

    #pragma unroll
    for (int jj = 0; jj < 8; ++jj) {
        int sig = 16 * (jj >> 2) + 4 * g + (jj & 3);
        tmp[jj] = (js0 < 20) ? Wf1[sig * 20 + js0] : 0.0f;
    }
    pack8(tmp, A0);
    #pragma unroll
    for (int jj = 0; jj < 8; ++jj) {
        int sig = 16 * (jj >> 2) + 4 * g + (jj & 3);
        tmp[jj] = (js1 < 20) ? Wf1[sig * 20 + js1] : 0.0f;
    }
    pack8(tmp, A1);
    #pragma unroll
    for (int jj = 0; jj < 8; ++jj) {
        int kx = 8 * g + jj;
        tmp[jj] = (js0 < 20) ? Wf1[(32 + kx) * 20 + js0] : 0.0f;
    }
    pack8(tmp, X0);
    #pragma unroll
    for (int jj = 0; jj < 8; ++jj) {
        int kx = 8 * g + jj;
        tmp[jj] = (js1 < 20) ? Wf1[(32 + kx) * 20 + js1] : 0.0f;
    }
    pack8(tmp, X1);
    #pragma unroll
    for (int jj = 0; jj < 8; ++jj) {
        int j = 8 * g + jj;
        tmp[jj] = (j < 20) ? Wf2[j * 32 + m] : 0.0f;
    }
    pack8(tmp, W0);
    #pragma unroll
    for (int jj = 0; jj < 8; ++jj) {
        int j = 8 * g + jj;
        tmp[jj] = (j < 20) ? Wf2[j * 32 + 16 + m] : 0.0f;
    }
    pack8(tmp, W1);

    f4 bias0, bias1, cb0, cb1;
    #pragma unroll
    for (int r = 0; r < 4; ++r) {
        bias0[r] = bf2[4 * g + r];
        bias1[r] = bf2[16 + 4 * g + r];
        int j0 = 8 * g + r;     cb0[r] = (j0 < 20) ? bf1[j0] : 0.0f;
        int j1 = 8 * g + r + 4; cb1[r] = (j1 < 20) ? bf1[j1] : 0.0f;
    }

    const float* xe  = x  + (size_t)e * T_SEQ * 32;
    const float* xp  = xe + 8 * g;
    const float* dte = dt + (size_t)e * T_SEQ * 2;
    uint32_t* zrow = zws + (size_t)e * T_SEQ * 16 + 4 * g;   // lane's dwordx4 slot

    struct XR { float4 a, b; };
    auto ldrow = [&](XR& r, int t) {
        const float* base = xp + (size_t)t * 32;
        r.a = *(const float4*)(base);
        r.b = *(const float4*)(base + 4);
    };

    // ---- preamble loads (in flight across z0 encode) ----
    XR P0, P1, Q0, Q1;
    float4 Pd, Qd;
    ldrow(P0, 0); ldrow(P1, 1); Pd = *(const float4*)(dte);
    ldrow(Q0, 2); ldrow(Q1, 3); Qd = *(const float4*)(dte + 4);

    // ---- z0 encode (scalar fp32, once) ----
    float z[8];
    {
        float x0v[32];
        #pragma unroll
        for (int i = 0; i < 32; i += 4) {
            float4 v = *(const float4*)(xe + i);
            x0v[i] = v.x; x0v[i+1] = v.y; x0v[i+2] = v.z; x0v[i+3] = v.w;
        }
        float h10[10];
        #pragma unroll
        for (int r = 0; r < 10; ++r) {
            float s = be1[r];
            #pragma unroll
            for (int i = 0; i < 32; ++i) s += x0v[i] * We1[i * 10 + r];
            h10[r] = fast_tanh(s);
        }
        #pragma unroll
        for (int jj = 0; jj < 8; ++jj) {
            int sig = 16 * (jj >> 2) + 4 * g + (jj & 3);
            float s = be2[sig];
            #pragma unroll
            for (int r = 0; r < 10; ++r) s += h10[r] * We2[r * 32 + sig];
            z[jj] = fast_tanh(s);
        }
    }

    bfrag zf; pack8(z, zf);      // carried fragment: store image == feval B operand

    auto cxcalc = [&](const XR& r, float d0, float d1, f4& c0, f4& c1, float& sc) {
        float xt[8] = { r.a.x, r.a.y, r.a.z, r.a.w, r.b.x, r.b.y, r.b.z, r.b.w };
        bfrag xf; pack8(xt, xf);
        c0 = mfma_(X0, xf, cb0);
        c1 = mfma_(X1, xf, cb1);
        sc = (d1 - d0) * 0.01f;
    };

    // Euler body: z += f(z) using carried zf; repack zf; store.
    auto body = [&](const f4& c0, const f4& c1, float sc, int t) {
        f4 p0 = mfma_(A0, zf, c0);
        f4 p1 = mfma_(A1, zf, c1);
        float pr[8];
        #pragma unroll
        for (int r = 0; r < 4; ++r) {
            pr[r]     = fmaxf(p0[r], 0.0f);
            pr[4 + r] = fmaxf(p1[r], 0.0f);
        }
        bfrag pf; pack8(pr, pf);
        f4 o0 = mfma_(W0, pf, bias0);
        f4 o1 = mfma_(W1, pf, bias1);
        const float s2 = sc + sc;
        #pragma unroll
        for (int r = 0; r < 4; ++r) {
            z[r]     += tanh_mul(o0[r], sc, s2);
            z[4 + r] += tanh_mul(o1[r], sc, s2);
        }
        pack8(z, zf);
        FragU Pu; Pu.v = zf;
        *(uint4*)(zrow + (uint32_t)t * 16) = make_uint4(Pu.u[0], Pu.u[1], Pu.u[2], Pu.u[3]);
    };

    f4 cA0, cA1, cB0, cB1;
    float sA, sB;
    cxcalc(P0, Pd.x, Pd.y, cA0, cA1, sA);    // cx for t=0

    #pragma unroll 1
    for (int k = 0; k < 24; ++k) {
        const int t = 4 * k;
        body(cA0, cA1, sA, t);
        cxcalc(P1, Pd.z, Pd.w, cB0, cB1, sB);          // row t+1 (loaded prev iter)
        ldrow(P0, t + 4); ldrow(P1, t + 5);            // P free -> prefetch t+4,t+5
        Pd = *(const float4*)(dte + 2 * (t + 4));
        body(cB0, cB1, sB, t + 1);
        cxcalc(Q0, Qd.x, Qd.y, cA0, cA1, sA);          // row t+2
        body(cA0, cA1, sA, t + 2);
        cxcalc(Q1, Qd.z, Qd.w, cB0, cB1, sB);          // row t+3
        ldrow(Q0, t + 6); ldrow(Q1, t + 7);            // Q free -> prefetch t+6,t+7
        Qd = *(const float4*)(dte + 2 * (t + 6));
        body(cB0, cB1, sB, t + 3);
        cxcalc(P0, Pd.x, Pd.y, cA0, cA1, sA);          // row t+4 (~2 bodies after load)
    }

    // Peeled final iteration (t=96..99): buffers hold rows 96..99, no prefetch.
    body(cA0, cA1, sA, 96);
    cxcalc(P1, Pd.z, Pd.w, cB0, cB1, sB);
    body(cB0, cB1, sB, 97);
    cxcalc(Q0, Qd.x, Qd.y, cA0, cA1, sA);
    body(cA0, cA1, sA, 98);
    cxcalc(Q1, Qd.z, Qd.w, cB0, cB1, sB);
    body(cB0, cB1, sB, 99);
}

// Parallel mu head: one thread per (e,t) row. Unpacks the permuted z layout:
// dword d: g=d>>2, q=d&3 -> component c=(q>>1)*16+4g+2(q&1) (lo), c+1 (hi).
__global__ __launch_bounds__(256, 4)
void mu_kernel(const uint32_t* __restrict__ zws,
               const float* __restrict__ Wm1, const float* __restrict__ bm1,
               const float* __restrict__ Wm2, const float* __restrict__ bm2,
               float* __restrict__ out, int nrows)
{
    int row = blockIdx.x * 256 + threadIdx.x;
    if (row >= nrows) return;
    const uint4* zp = (const uint4*)(zws + (size_t)row * 16);
    uint4 q0 = zp[0], q1 = zp[1], q2 = zp[2], q3 = zp[3];
    uint32_t du[16] = { q0.x, q0.y, q0.z, q0.w, q1.x, q1.y, q1.z, q1.w,
                        q2.x, q2.y, q2.z, q2.w, q3.x, q3.y, q3.z, q3.w };
    float zf[32];
    #pragma unroll
    for (int d = 0; d < 16; ++d) {
        int gg = d >> 2, qq = d & 3;
        int c = (qq >> 1) * 16 + 4 * gg + (qq & 1) * 2;
        uint32_t u = du[d];
        zf[c]     = __uint_as_float(u << 16);
        zf[c + 1] = __uint_as_float(u & 0xFFFF0000u);
    }
    float v[10];
    #pragma unroll
    for (int r = 0; r < 10; ++r) v[r] = bm1[r];
    #pragma unroll
    for (int i = 0; i < 32; ++i) {
        float zi = zf[i];
        #pragma unroll
        for (int r = 0; r < 10; ++r) v[r] = fmaf(zi, Wm1[i * 10 + r], v[r]);
    }
    float mu = bm2[0];
    #pragma unroll
    for (int r = 0; r < 10; ++r) mu += fast_tanh(v[r]) * Wm2[r];
    out[row] = mu;
}

// ============================================================================
// Fallback (ws too small / B not /16): fused Euler, mu in-loop (r9 structure).
// ============================================================================
__global__ __launch_bounds__(64, 1)
void latode_fused(const float* __restrict__ dt,  const float* __restrict__ x,
                  const float* __restrict__ We1, const float* __restrict__ be1,
                  const float* __restrict__ We2, const float* __restrict__ be2,
                  const float* __restrict__ Wf1, const float* __restrict__ bf1,
                  const float* __restrict__ Wf2, const float* __restrict__ bf2,
                  const float* __restrict__ Wm1, const float* __restrict__ bm1,
                  const float* __restrict__ Wm2, const float* __restrict__ bm2,
                  float* __restrict__ out, int B)
{
    const int l = threadIdx.x;
    const int g = l >> 4;
    const int m = l & 15;
    const int e = blockIdx.x * 16 + m;
    if (e >= B) return;
    const int js0 = 8 * (m >> 2) + (m & 3);
    const int js1 = js0 + 4;

    float tmp[8];
    bfrag A0, A1, X0, X1, W0, W1, M0;
    #pragma unroll
    for (int jj = 0; jj < 8; ++jj) {
        int sig = 16 * (jj >> 2) + 4 * g + (jj & 3);
        tmp[jj] = (js0 < 20) ? Wf1[sig * 20 + js0] : 0.0f;
    }
    pack8(tmp, A0);
    #pragma unroll
    for (int jj = 0; jj < 8; ++jj) {
        int sig = 16 * (jj >> 2) + 4 * g + (jj & 3);
        tmp[jj] = (js1 < 20) ? Wf1[sig * 20 + js1] : 0.0f;
    }
    pack8(tmp, A1);
    #pragma unroll
    for (int jj = 0; jj < 8; ++jj) {
        int kx = 8 * g + jj;
        tmp[jj] = (js0 < 20) ? Wf1[(32 + kx) * 20 + js0] : 0.0f;
    }
    pack8(tmp, X0);
    #pragma unroll
    for (int jj = 0; jj < 8; ++jj) {
        int kx = 8 * g + jj;
        tmp[jj] = (js1 < 20) ? Wf1[(32 + kx) * 20 + js1] : 0.0f;
    }
    pack8(tmp, X1);
    #pragma unroll
    for (int jj = 0; jj < 8; ++jj) {
        int j = 8 * g + jj;
        tmp[jj] = (j < 20) ? Wf2[j * 32 + m] : 0.0f;
    }
    pack8(tmp, W0);
    #pragma unroll
    for (int jj = 0; jj < 8; ++jj) {
        int j = 8 * g + jj;
        tmp[jj] = (j < 20) ? Wf2[j * 32 + 16 + m] : 0.0f;
    }
    pack8(tmp, W1);
    #pragma unroll
    for (int jj = 0; jj < 8; ++jj) {
        int sig = 16 * (jj >> 2) + 4 * g + (jj & 3);
        tmp[jj] = (m < 10) ? Wm1[sig * 10 + m] : 0.0f;
    }
    pack8(tmp, M0);

    f4 bias0, bias1, cb0, cb1, bmv;
    float wm2r[4];
    #pragma unroll
    for (int r = 0; r < 4; ++r) {
        bias0[r] = bf2[4 * g + r];
        bias1[r] = bf2[16 + 4 * g + r];
        int j0 = 8 * g + r;     cb0[r] = (j0 < 20) ? bf1[j0] : 0.0f;
        int j1 = 8 * g + r + 4; cb1[r] = (j1 < 20) ? bf1[j1] : 0.0f;
        int vr = 4 * g + r;
        bmv[r]  = (vr < 10) ? bm1[vr] : 0.0f;
        wm2r[r] = (vr < 10) ? Wm2[vr] : 0.0f;
    }

    const float* xe  = x  + (size_t)e * T_SEQ * 32;
    const float* dte = dt + (size_t)e * T_SEQ * 2;

    float z[8];
    {
        float x0v[32];
        #pragma unroll
        for (int i = 0; i < 32; i += 4) {
            float4 v = *(const float4*)(xe + i);
            x0v[i] = v.x; x0v[i+1] = v.y; x0v[i+2] = v.z; x0v[i+3] = v.w;
        }
        float h10[10];
        #pragma unroll
        for (int r = 0; r < 10; ++r) {
            float s = be1[r];
            #pragma unroll
            for (int i = 0; i < 32; ++i) s += x0v[i] * We1[i * 10 + r];
            h10[r] = fast_tanh(s);
        }
        #pragma unroll
        for (int jj = 0; jj < 8; ++jj) {
            int sig = 16 * (jj >> 2) + 4 * g + (jj & 3);
            float s = be2[sig];
            #pragma unroll
            for (int r = 0; r < 10; ++r) s += h10[r] * We2[r * 32 + sig];
            z[jj] = fast_tanh(s);
        }
    }

    const float bm2s = bm2[0];
    f4 cx0, cx1;
    float scale;
    {
        float4 va = *(const float4*)(xe + 8 * g);
        float4 vb = *(const float4*)(xe + 8 * g + 4);
        float2 dd = *(const float2*)(dte);
        float xt[8] = { va.x, va.y, va.z, va.w, vb.x, vb.y, vb.z, vb.w };
        bfrag xf; pack8(xt, xf);
        cx0 = mfma_(X0, xf, cb0);
        cx1 = mfma_(X1, xf, cb1);
        scale = (dd.y - dd.x) * 0.01f;
    }

    for (int t = 0; t < T_SEQ; ++t) {
        int tn = (t + 1 < T_SEQ) ? (t + 1) : t;
        const float* xr = xe + tn * 32 + 8 * g;
        float4 na = *(const float4*)(xr);
        float4 nb = *(const float4*)(xr + 4);
        float2 nd = *(const float2*)(dte + 2 * tn);
        const float s2 = scale + scale;

        bfrag bb; pack8(z, bb);
        f4 p0 = mfma_(A0, bb, cx0);
        f4 p1 = mfma_(A1, bb, cx1);
        float pr[8];
        #pragma unroll
        for (int r = 0; r < 4; ++r) {
            pr[r]     = fmaxf(p0[r], 0.0f);
            pr[4 + r] = fmaxf(p1[r], 0.0f);
        }
        bfrag pf; pack8(pr, pf);
        f4 o0 = mfma_(W0, pf, bias0);
        f4 o1 = mfma_(W1, pf, bias1);
        #pragma unroll
        for (int r = 0; r < 4; ++r) {
            z[r]     += tanh_mul(o0[r], scale, s2);
            z[4 + r] += tanh_mul(o1[r], scale, s2);
        }

        {
            float xt[8] = { na.x, na.y, na.z, na.w, nb.x, nb.y, nb.z, nb.w };
            bfrag xf; pack8(xt, xf);
            cx0 = mfma_(X0, xf, cb0);
            cx1 = mfma_(X1, xf, cb1);
            scale = (nd.y - nd.x) * 0.01f;
        }

        bfrag zf; pack8(z, zf);
        f4 vv = mfma_(M0, zf, bmv);
        float p = 0.0f;
        #pragma unroll
        for (int r = 0; r < 4; ++r) p += fast_tanh(vv[r]) * wm2r[r];
        p += __shfl_xor(p, 16, 64);
        p += __shfl_xor(p, 32, 64);
        if (l < 16) out[(size_t)e * T_SEQ + t] = p + bm2s;
    }
}

extern "C" void kernel_launch(void* const* d_in, const int* in_sizes, int n_in,
                              void* d_out, int out_size, void* d_ws, size_t ws_size,
                              hipStream_t stream) {
    const float* dt  = (const float*)d_in[0];
    const float* x   = (const float*)d_in[1];
    const float* We1 = (const float*)d_in[2];
    const float* be1 = (const float*)d_in[3];
    const float* We2 = (const float*)d_in[4];
    const float* be2 = (const float*)d_in[5];
    const float* Wf1 = (const float*)d_in[6];
    const float* bf1 = (const float*)d_in[7];
    const float* Wf2 = (const float*)d_in[8];
    const float* bf2 = (const float*)d_in[9];
    const float* Wm1 = (const float*)d_in[10];
    const float* bm1 = (const float*)d_in[11];
    const float* Wm2 = (const float*)d_in[12];
    const float* bm2 = (const float*)d_in[13];
    float* out = (float*)d_out;

    const int B = in_sizes[0] / (T_SEQ * 2);   // 8192
    const size_t zbytes = (size_t)B * T_SEQ * 32 * 2;

    if (ws_size >= zbytes && (B % 16) == 0) {
        hipLaunchKernelGGL(latode_serial, dim3(B / 16), dim3(64), 0, stream,
                           dt, x, We1, be1, We2, be2, Wf1, bf1, Wf2, bf2,
                           (uint32_t*)d_ws, B);
        int nrows = B * T_SEQ;
        hipLaunchKernelGGL(mu_kernel, dim3((nrows + 255) / 256), dim3(256), 0, stream,
                           (const uint32_t*)d_ws, Wm1, bm1, Wm2, bm2, out, nrows);
    } else {
        hipLaunchKernelGGL(latode_fused, dim3((B + 15) / 16), dim3(64), 0, stream,
                           dt, x, We1, be1, We2, be2, Wf1, bf1, Wf2, bf2,
                           Wm1, bm1, Wm2, bm2, out, B);
    }
}